// Round 9
// baseline (304.758 us; speedup 1.0000x reference)
//
#include <hip/hip_runtime.h>

typedef unsigned short u16;
typedef __attribute__((ext_vector_type(8))) short bf8_t;    // 8 x bf16 (4 VGPRs)
typedef __attribute__((ext_vector_type(4))) float f4_t;     // 4 x f32
typedef __attribute__((ext_vector_type(4))) unsigned short u16x4;
typedef __attribute__((ext_vector_type(8))) unsigned short u16x8;

__device__ __forceinline__ float b2f(u16 h) {
  union { unsigned u; float f; } v; v.u = ((unsigned)h) << 16; return v.f;
}
__device__ __forceinline__ u16 f2b(float f) {
  union { float f; unsigned u; } v; v.f = f;
  unsigned u = v.u;
  u += 0x7fffu + ((u >> 16) & 1u);   // round-nearest-even
  return (u16)(u >> 16);
}

#define AS1C(p) ((const __attribute__((address_space(1))) void*)(p))
#define AS3(p)  ((__attribute__((address_space(3))) void*)(p))

// one fused f32 -> bf16 convert over all 5 weight/input arrays
__global__ __launch_bounds__(256)
void cvt_all(const float* __restrict__ x, const float* __restrict__ inW,
             const float* __restrict__ xprojW, const float* __restrict__ dtW,
             const float* __restrict__ outW,
             u16* __restrict__ xb, u16* __restrict__ inWb, u16* __restrict__ xpb,
             u16* __restrict__ dtWb, u16* __restrict__ outWb)
{
  int i = blockIdx.x * 256 + threadIdx.x;      // float4 index, total 2703360
  if (i >= 2703360) return;
  const float* s; u16* d; int off;
  if (i < 1048576)      { s = x;      d = xb;    off = i; }
  else if (i < 2097152) { s = inW;    d = inWb;  off = i - 1048576; }
  else if (i < 2146304) { s = xprojW; d = xpb;   off = i - 2097152; }
  else if (i < 2179072) { s = dtW;    d = dtWb;  off = i - 2146304; }
  else                  { s = outW;   d = outWb; off = i - 2179072; }
  f4_t v = *(const f4_t*)(s + (size_t)off * 4);
  u16x4 o;
#pragma unroll
  for (int j = 0; j < 4; ++j) o[j] = f2b(v[j]);
  *(u16x4*)(d + (size_t)off * 4) = o;
}

// Stage one 128x64 bf16 tile (16 KB) into LDS, XOR-swizzled: granule (r,q)
// holds global colchunk q^(r&7). Staging lane i (chunk of 8 rows) fetches
// colchunk (i&7)^((i>>3)&7); reader uses granule (g ^ (row&7)). Bank-quad
// depends only on q_l -> 8 lanes per 4-bank group = 2/bank = conflict-free.
__device__ __forceinline__ void stage64(const u16* g, int ld, int row0, int rowmax,
                                        int k0, u16* lds, int wid, int lane) {
  int qg = (lane & 7) ^ ((lane >> 3) & 7);
#pragma unroll
  for (int c = 0; c < 4; ++c) {
    int chunk = wid * 4 + c;
    int r = row0 + chunk * 8 + (lane >> 3);
    if (r > rowmax) r = rowmax;                       // clamp (results discarded later)
    const u16* gp = g + (size_t)r * ld + k0 + qg * 8;
    __builtin_amdgcn_global_load_lds(AS1C(gp), AS3(lds + chunk * 512), 16, 0, 0);
  }
}

// C = A * Bt^T : A[M,K] bf16 row-major (lda), Bt[N,K] bf16 row-major (ldb).
// BK=64 (two 32-k half-steps per barrier epoch).
// EPI 1: x_proj   -> split-K partials in BF16: o16[(bx*4096+m)*96+n], n<96
// EPI 2: dt_proj  -> o16[m*2048+n] = bf16(softplus(acc + biasf[n]))
template<int EPI>
__device__ __forceinline__ void gemm_body(const u16* __restrict__ A, int lda,
             const u16* __restrict__ Bt, int ldb,
             int Kblk, int Nact,
             u16* __restrict__ o16, const float* __restrict__ biasf)
{
  __shared__ u16 lsA[128 * 64];
  __shared__ u16 lsB[128 * 64];
  const int tid = threadIdx.x;
  const int wid = tid >> 6, lane = tid & 63;
  const int wm = wid >> 1, wn = wid & 1;          // 2x2 wave grid, 64x64 each
  const int lrow = lane & 15;
  const int kq = lane >> 4;                       // 0..3
  const int sw = lrow & 7;                        // swizzle key
  const int m0 = blockIdx.y * 128;
  const int n0 = (EPI == 1) ? 0 : blockIdx.x * 128;
  int kbase = 0;
  if (EPI == 1) kbase = blockIdx.x * Kblk;

  f4_t acc[4][4];
#pragma unroll
  for (int i = 0; i < 4; ++i)
#pragma unroll
    for (int j = 0; j < 4; ++j) acc[i][j] = {0.f, 0.f, 0.f, 0.f};

  for (int kt = kbase; kt < kbase + Kblk; kt += 64) {
    stage64(A,  lda, m0, 0x3fffffff, kt, lsA, wid, lane);
    stage64(Bt, ldb, n0, Nact - 1,   kt, lsB, wid, lane);
    __syncthreads();
#pragma unroll
    for (int h = 0; h < 2; ++h) {
      const int lk = ((h * 4 + kq) ^ sw) * 8;
      bf8_t af[4], bfr[4];
#pragma unroll
      for (int mi = 0; mi < 4; ++mi)
        af[mi] = *(const bf8_t*)&lsA[(wm * 64 + mi * 16 + lrow) * 64 + lk];
#pragma unroll
      for (int ni = 0; ni < 4; ++ni)
        bfr[ni] = *(const bf8_t*)&lsB[(wn * 64 + ni * 16 + lrow) * 64 + lk];
#pragma unroll
      for (int mi = 0; mi < 4; ++mi)
#pragma unroll
        for (int ni = 0; ni < 4; ++ni)
          acc[mi][ni] = __builtin_amdgcn_mfma_f32_16x16x32_bf16(af[mi], bfr[ni], acc[mi][ni], 0, 0, 0);
    }
    __syncthreads();
  }

  const int rq = (lane >> 4) * 4;                  // C/D: row=(lane>>4)*4+r, col=lane&15
#pragma unroll
  for (int mi = 0; mi < 4; ++mi) {
#pragma unroll
    for (int ni = 0; ni < 4; ++ni) {
#pragma unroll
      for (int r = 0; r < 4; ++r) {
        int m = m0 + wm * 64 + mi * 16 + rq + r;
        int n = n0 + wn * 64 + ni * 16 + lrow;
        float v = acc[mi][ni][r];
        if (EPI == 1) {
          if (n < 96) o16[((size_t)blockIdx.x * 4096 + m) * 96 + n] = f2b(v);
        } else if (EPI == 2) {
          float t = v + biasf[n];
          float sp = (t > 20.f) ? t : log1pf(__expf(t));
          o16[(size_t)m * 2048 + n] = f2b(sp);
        }
      }
    }
  }
}

__global__ __launch_bounds__(256)
void gemm_xp(const u16* A, int lda, const u16* Bt, int ldb, int Kblk, int Nact,
             u16* o16, const float* biasf)
{ gemm_body<1>(A, lda, Bt, ldb, Kblk, Nact, o16, biasf); }

__global__ __launch_bounds__(256)
void gemm_dt(const u16* A, int lda, const u16* Bt, int ldb, int Kblk, int Nact,
             u16* o16, const float* biasf)
{ gemm_body<2>(A, lda, Bt, ldb, Kblk, Nact, o16, biasf); }

// ---------------------------------------------------------------------------
// 8-phase 256x256 bf16 GEMM for in_proj (M=N=4096, K=1024): verified R1/R2
// (42.1-42.3 us, 826 TF). Structure ceiling analysis (R5): acc[8][4]=128 f32
// -> ~256 unified regs/wave -> hard 1 block/CU; 128^2 tiles would be LDS-BW
// bound (~38 us); intra-block schedule perturbations null (R3/R4). Final.
// ---------------------------------------------------------------------------

// stage one 128x64 unit: 512 threads x 2 x 16B gload_lds. granule g = j*512 +
// wid*64 + lane -> lds row g>>3, slot g&7, global colchunk (g&7)^((g>>3)&7).
__device__ __forceinline__ void stageu(const u16* __restrict__ g, int ld,
                                       int row0, int k0, u16* ldsu,
                                       int wid, int lane) {
  int qg = (lane & 7) ^ ((lane >> 3) & 7);
#pragma unroll
  for (int j = 0; j < 2; ++j) {
    int rr = j * 64 + wid * 8 + (lane >> 3);
    const u16* gp = g + (size_t)(row0 + rr) * ld + k0 + qg * 8;
    __builtin_amdgcn_global_load_lds(AS1C(gp), AS3(ldsu + (j * 512 + wid * 64) * 8), 16, 0, 0);
  }
}

#define G8_BAR()   __builtin_amdgcn_s_barrier()
#define G8_LGKM0() do { asm volatile("s_waitcnt lgkmcnt(0)" ::: "memory"); \
                        __builtin_amdgcn_sched_barrier(0); } while (0)
#define G8_LGKM8() asm volatile("s_waitcnt lgkmcnt(8)" ::: "memory")
#define G8_VM(N)   do { asm volatile("s_waitcnt vmcnt(" #N ")" ::: "memory"); \
                        __builtin_amdgcn_sched_barrier(0); } while (0)

#define RD_A(base, MH) do { \
  _Pragma("unroll") \
  for (int mi_ = 0; mi_ < 4; ++mi_) { \
    af[mi_][0] = *(const bf8_t*)((base) + arow + ((MH) * 64 + mi_ * 16) * 64 + aq0); \
    af[mi_][1] = *(const bf8_t*)((base) + arow + ((MH) * 64 + mi_ * 16) * 64 + aq1); \
  } } while (0)

#define RD_B(base, NH) do { \
  _Pragma("unroll") \
  for (int ni_ = 0; ni_ < 2; ++ni_) { \
    bfr[NH][ni_][0] = *(const bf8_t*)((base) + brow + ((NH) * 32 + ni_ * 16) * 64 + aq0); \
    bfr[NH][ni_][1] = *(const bf8_t*)((base) + brow + ((NH) * 32 + ni_ * 16) * 64 + aq1); \
  } } while (0)

#define MMA(MH, NH) do { \
  __builtin_amdgcn_s_setprio(1); \
  _Pragma("unroll") \
  for (int mi_ = 0; mi_ < 4; ++mi_) \
    _Pragma("unroll") \
    for (int ni_ = 0; ni_ < 2; ++ni_) { \
      acc[(MH) * 4 + mi_][(NH) * 2 + ni_] = __builtin_amdgcn_mfma_f32_16x16x32_bf16( \
          af[mi_][0], bfr[NH][ni_][0], acc[(MH) * 4 + mi_][(NH) * 2 + ni_], 0, 0, 0); \
      acc[(MH) * 4 + mi_][(NH) * 2 + ni_] = __builtin_amdgcn_mfma_f32_16x16x32_bf16( \
          af[mi_][1], bfr[NH][ni_][1], acc[(MH) * 4 + mi_][(NH) * 2 + ni_], 0, 0, 0); \
    } \
  __builtin_amdgcn_s_setprio(0); \
} while (0)

__global__ __launch_bounds__(512, 2)
void gemm8_in(const u16* __restrict__ A, const u16* __restrict__ Bt,
              u16* __restrict__ o16)
{
  __shared__ u16 ls[65536];                       // 128 KB: 2 buf x (A 32K + B 32K)
  const int tid = threadIdx.x;
  const int wid = tid >> 6, lane = tid & 63;
  const int wm = wid >> 2, wn = wid & 3;          // 2x4 wave grid, 128x64 per wave
  const int lrow = lane & 15;
  const int kq = lane >> 4;
  const int sw = lrow & 7;
  const int m0 = blockIdx.y * 256;
  const int n0 = blockIdx.x * 256;
  u16* lsA0 = ls;
  u16* lsB0 = ls + 16384;
  u16* lsA1 = ls + 32768;
  u16* lsB1 = ls + 49152;
  const int arow = (wm * 128 + lrow) * 64;
  const int brow = (wn * 64 + lrow) * 64;
  const int aq0 = (kq ^ sw) * 8;
  const int aq1 = ((4 + kq) ^ sw) * 8;

  f4_t acc[8][4];
#pragma unroll
  for (int i = 0; i < 8; ++i)
#pragma unroll
    for (int j = 0; j < 4; ++j) acc[i][j] = {0.f, 0.f, 0.f, 0.f};
  bf8_t af[4][2];
  bf8_t bfr[2][2][2];

  // prologue: tile0 (A0,A1,B0,B1)->buf0, tile1 (B0,B1)->buf1; keep 4 in flight
  stageu(A,  1024, m0,        0, lsA0,        wid, lane);
  stageu(A,  1024, m0 + 128,  0, lsA0 + 8192, wid, lane);
  stageu(Bt, 1024, n0,        0, lsB0,        wid, lane);
  stageu(Bt, 1024, n0 + 128,  0, lsB0 + 8192, wid, lane);
  stageu(Bt, 1024, n0,       64, lsB1,        wid, lane);
  stageu(Bt, 1024, n0 + 128, 64, lsB1 + 8192, wid, lane);
  G8_VM(4); G8_BAR();

#pragma unroll 1
  for (int i = 0; i < 7; ++i) {                   // iterations 0..6 (tiles 0..13)
    const int k1 = (2 * i + 1) * 64, k2 = k1 + 64, k3 = k1 + 128;
    // P1: read buf0 A-half0 + B-half0; stage (t+1).A0 -> buf1
    RD_A(lsA0, 0); RD_B(lsB0, 0);
    stageu(A, 1024, m0, k1, lsA1, wid, lane);
    G8_LGKM8(); G8_BAR(); G8_LGKM0(); MMA(0, 0); G8_BAR();
    // P2: read buf0 B-half1; stage (t+1).A1 -> buf1
    RD_B(lsB0, 1);
    stageu(A, 1024, m0 + 128, k1, lsA1 + 8192, wid, lane);
    G8_BAR(); G8_LGKM0(); MMA(0, 1); G8_BAR();
    // P3: read buf0 A-half1; stage (t+2).B0 -> buf0 (B reads done end P2)
    RD_A(lsA0, 1);
    stageu(Bt, 1024, n0, k2, lsB0, wid, lane);
    G8_BAR(); G8_LGKM0(); MMA(1, 0); G8_BAR();
    // P4: stage (t+2).B1 -> buf0; counted vmcnt -> tile t+1 landed
    stageu(Bt, 1024, n0 + 128, k2, lsB0 + 8192, wid, lane);
    G8_BAR(); G8_LGKM0(); MMA(1, 1); G8_VM(4); G8_BAR();
    // P5: read buf1 A-half0 + B-half0; stage (t+2).A0 -> buf0 (A reads done end P3)
    RD_A(lsA1, 0); RD_B(lsB1, 0);
    stageu(A, 1024, m0, k2, lsA0, wid, lane);
    G8_LGKM8(); G8_BAR(); G8_LGKM0(); MMA(0, 0); G8_BAR();
    // P6: read buf1 B-half1; stage (t+2).A1 -> buf0
    RD_B(lsB1, 1);
    stageu(A, 1024, m0 + 128, k2, lsA0 + 8192, wid, lane);
    G8_BAR(); G8_LGKM0(); MMA(0, 1); G8_BAR();
    // P7: read buf1 A-half1; stage (t+3).B0 -> buf1
    RD_A(lsA1, 1);
    stageu(Bt, 1024, n0, k3, lsB1, wid, lane);
    G8_BAR(); G8_LGKM0(); MMA(1, 0); G8_BAR();
    // P8: stage (t+3).B1 -> buf1; counted vmcnt -> tile t+2 landed
    stageu(Bt, 1024, n0 + 128, k3, lsB1 + 8192, wid, lane);
    G8_BAR(); G8_LGKM0(); MMA(1, 1); G8_VM(4); G8_BAR();
  }

  {                                               // last iteration: tiles 14,15
    const int k1 = 960;
    RD_A(lsA0, 0); RD_B(lsB0, 0);
    stageu(A, 1024, m0, k1, lsA1, wid, lane);
    G8_LGKM8(); G8_BAR(); G8_LGKM0(); MMA(0, 0); G8_BAR();
    RD_B(lsB0, 1);
    stageu(A, 1024, m0 + 128, k1, lsA1 + 8192, wid, lane);
    G8_BAR(); G8_LGKM0(); MMA(0, 1); G8_BAR();
    RD_A(lsA0, 1);
    G8_BAR(); G8_LGKM0(); MMA(1, 0); G8_BAR();
    G8_BAR(); G8_LGKM0(); MMA(1, 1); G8_VM(0); G8_BAR();
    RD_A(lsA1, 0); RD_B(lsB1, 0);
    G8_BAR(); G8_LGKM0(); MMA(0, 0); G8_BAR();
    RD_B(lsB1, 1);
    G8_BAR(); G8_LGKM0(); MMA(0, 1); G8_BAR();
    RD_A(lsA1, 1);
    G8_BAR(); G8_LGKM0(); MMA(1, 0); G8_BAR();
    G8_LGKM0(); MMA(1, 1);
  }

  // epilogue: xi (n<2048) | z (n>=2048, at o16+8M)
  const int rq = (lane >> 4) * 4;
#pragma unroll
  for (int mi = 0; mi < 8; ++mi) {
#pragma unroll
    for (int ni = 0; ni < 4; ++ni) {
#pragma unroll
      for (int r = 0; r < 4; ++r) {
        int m = m0 + wm * 128 + mi * 16 + rq + r;
        int n = n0 + wn * 64 + ni * 16 + lrow;
        float v = acc[mi][ni][r];
        if (n < 2048) o16[(size_t)m * 2048 + n] = f2b(v);
        else          o16[(size_t)8388608 + (size_t)m * 2048 + (n - 2048)] = f2b(v);
      }
    }
  }
}

// ---------------------------------------------------------------------------
// R9 out_proj: A-in-LDS / B-in-REGISTERS GEMM. Theory: the R8 version was
// LDS-read-throughput-bound (128 ds_read_b128/CU/K-tile x 12 cyc = 1536 cyc
// x 32 tiles = 20.5 us ~= its runtime). Moving B to direct global->VGPR
// fragment loads (outWb is 4.2 MB, 32-block reuse -> L2/L3-hot; registers
// need no bank swizzle) halves LDS reads -> LDS-serial ~10.2 us.
// 256 thr, 2x2 waves of 64x64, tile 128Mx128N, K=2048, grid (8,32), 32 KB
// LDS (A-dbuf only), 2 blk/CU. Fused residual: h = bf16(y + x).
// Ledger (per thread: stageA=4 vm, loadB=8 vm): prologue A0,B0,A1,B1 = 24;
// vmcnt(12) -> tile0 landed. Each phase: +A(t+2)4 +B(t+2)8, vmcnt(12)
// retires tile t+1. B-loads issued AFTER the MFMA consuming the old frags
// (in-order issue); A-stage after lgkm-drain + barrier (region sealed).
// ---------------------------------------------------------------------------

#define X5_RD_A(base) do { \
  _Pragma("unroll") \
  for (int mi_ = 0; mi_ < 4; ++mi_) { \
    afx[mi_][0] = *(const bf8_t*)((base) + (wm * 64 + mi_ * 16 + lrow) * 64 + aq0); \
    afx[mi_][1] = *(const bf8_t*)((base) + (wm * 64 + mi_ * 16 + lrow) * 64 + aq1); \
  } } while (0)

#define X5_LD_B(dst, kt) do { \
  _Pragma("unroll") \
  for (int ni_ = 0; ni_ < 4; ++ni_) { \
    const u16* bp_ = Bt + (size_t)(n0 + wn * 64 + ni_ * 16 + lrow) * 2048 + (kt) + kq * 8; \
    dst[ni_][0] = *(const bf8_t*)(bp_); \
    dst[ni_][1] = *(const bf8_t*)(bp_ + 32); \
  } } while (0)

#define X5_MMA(breg) do { \
  __builtin_amdgcn_s_setprio(1); \
  _Pragma("unroll") \
  for (int mi_ = 0; mi_ < 4; ++mi_) \
    _Pragma("unroll") \
    for (int ni_ = 0; ni_ < 4; ++ni_) { \
      acc[mi_][ni_] = __builtin_amdgcn_mfma_f32_16x16x32_bf16( \
          afx[mi_][0], breg[ni_][0], acc[mi_][ni_], 0, 0, 0); \
      acc[mi_][ni_] = __builtin_amdgcn_mfma_f32_16x16x32_bf16( \
          afx[mi_][1], breg[ni_][1], acc[mi_][ni_], 0, 0, 0); \
    } \
  __builtin_amdgcn_s_setprio(0); \
} while (0)

__global__ __launch_bounds__(256, 2)
void gemm4_out(const u16* __restrict__ A, const u16* __restrict__ Bt,
               const float* __restrict__ xres, u16* __restrict__ hout)
{
  __shared__ u16 ls[16384];                       // 32 KB: 2 x A-buf (128x64)
  const int tid = threadIdx.x;
  const int wid = tid >> 6, lane = tid & 63;
  const int wm = wid >> 1, wn = wid & 1;          // 2x2 waves, 64x64 each
  const int lrow = lane & 15;
  const int kq = lane >> 4;
  const int sw = lrow & 7;
  const int m0 = blockIdx.y * 128;
  const int n0 = blockIdx.x * 128;
  u16* lsA0 = ls;                                 // 8192 u16 = 128x64
  u16* lsA1 = ls + 8192;
  const int aq0 = (kq ^ sw) * 8;
  const int aq1 = ((4 + kq) ^ sw) * 8;

  f4_t acc[4][4];
#pragma unroll
  for (int i = 0; i < 4; ++i)
#pragma unroll
    for (int j = 0; j < 4; ++j) acc[i][j] = {0.f, 0.f, 0.f, 0.f};
  bf8_t afx[4][2];
  bf8_t b0[4][2], b1[4][2];                       // B frags, static-indexed

  // prologue: A0->ls0 (+4), B0->b0 (+8), A1->ls1 (+4), B1->b1 (+8) = 24
  stage64(A, 2048, m0, 0x3fffffff, 0, lsA0, wid, lane);
  X5_LD_B(b0, 0);
  stage64(A, 2048, m0, 0x3fffffff, 64, lsA1, wid, lane);
  X5_LD_B(b1, 64);
  G8_VM(12); G8_BAR();                            // tile0 (A0,B0) landed

#pragma unroll 1
  for (int i = 0; i < 15; ++i) {                  // tile pairs (0,1)..(28,29)
    const int ke = (2 * i + 2) * 64;              // tile t+2 (even)
    const int ko = ke + 64;                       // tile t+3 (odd)
    // even tile 2i: consume ls0/b0; stage A(t+2)->ls0; load B(t+2)->b0
    X5_RD_A(lsA0);
    G8_LGKM0(); G8_BAR();                         // ls0 reads drained, all waves
    stage64(A, 2048, m0, 0x3fffffff, ke, lsA0, wid, lane);
    X5_MMA(b0);                                   // consumes b0 (old)
    X5_LD_B(b0, ke);                              // refill b0 (issued post-MMA)
    G8_VM(12); G8_BAR();                          // tile t+1 landed
    // odd tile 2i+1: consume ls1/b1; stage A(t+3)->ls1; load B(t+3)->b1
    X5_RD_A(lsA1);
    G8_LGKM0(); G8_BAR();
    stage64(A, 2048, m0, 0x3fffffff, ko, lsA1, wid, lane);
    X5_MMA(b1);
    X5_LD_B(b1, ko);
    G8_VM(12); G8_BAR();                          // tile t+2 landed
  }

  {                                               // tiles 30, 31
    X5_RD_A(lsA0);
    G8_LGKM0(); G8_BAR();
    X5_MMA(b0);
    G8_VM(0); G8_BAR();                           // land A(31), B(31)
    X5_RD_A(lsA1);
    G8_LGKM0();
    X5_MMA(b1);
  }

  const int rq = (lane >> 4) * 4;
#pragma unroll
  for (int mi = 0; mi < 4; ++mi) {
#pragma unroll
    for (int ni = 0; ni < 4; ++ni) {
#pragma unroll
      for (int r = 0; r < 4; ++r) {
        int m = m0 + wm * 64 + mi * 16 + rq + r;
        int n = n0 + wn * 64 + ni * 16 + lrow;
        hout[(size_t)m * 1024 + n] = f2b(acc[mi][ni][r] + xres[(size_t)m * 1024 + n]);
      }
    }
  }
}

// reduce 8 bf16 split-K partials of x_proj; emit dtA bf16 [4096,64] + bc f32 [4096,32]
__global__ __launch_bounds__(256)
void xproj_reduce(const u16* __restrict__ part, u16* __restrict__ dtA,
                  float* __restrict__ bc)
{
  int idx = blockIdx.x * 256 + threadIdx.x;   // 4096*96
  int m = idx / 96, n = idx - m * 96;
  float s = 0.f;
#pragma unroll
  for (int p = 0; p < 8; ++p) s += b2f(part[(size_t)p * 393216 + idx]);
  if (n < 64) dtA[(size_t)m * 64 + n] = f2b(s);
  else        bc[(size_t)m * 32 + (n - 64)] = s;
}

// causal depthwise conv1d (window 4) + bias + silu.
// 4 output rows per thread -> 7 row-loads per 4 outputs (verified R8).
__global__ __launch_bounds__(256)
void conv_silu(const u16* __restrict__ xib, const float* __restrict__ cw,
               const float* __restrict__ cb, u16* __restrict__ ub)
{
  int i = blockIdx.x * 256 + threadIdx.x;     // 262,144 threads
  int c8 = (i & 255) * 8;
  int r0 = (i >> 8) * 4;                      // rows r0..r0+3 (same batch)
  int l0 = r0 & 2047;
  const u16* base = xib + (size_t)r0 * 2048 + c8;
  u16x8 xr[7];
  u16x8 z8 = {0,0,0,0,0,0,0,0};
#pragma unroll
  for (int j = 0; j < 3; ++j)
    xr[j] = (l0 != 0) ? *(const u16x8*)(base + (j - 3) * 2048) : z8;
#pragma unroll
  for (int j = 3; j < 7; ++j)
    xr[j] = *(const u16x8*)(base + (j - 3) * 2048);
  f4_t cb0 = *(const f4_t*)(cb + c8);
  f4_t cb1 = *(const f4_t*)(cb + c8 + 4);
  f4_t w[8];
#pragma unroll
  for (int j = 0; j < 8; ++j) w[j] = *(const f4_t*)(cw + (size_t)(c8 + j) * 4);
#pragma unroll
  for (int k = 0; k < 4; ++k) {
    u16x8 o;
#pragma unroll
    for (int j = 0; j < 8; ++j) {
      float a = (j < 4 ? cb0[j] : cb1[j - 4])
              + w[j][0] * b2f(xr[k][j])     + w[j][1] * b2f(xr[k + 1][j])
              + w[j][2] * b2f(xr[k + 2][j]) + w[j][3] * b2f(xr[k + 3][j]);
      float s = a / (1.f + __expf(-a));
      o[j] = f2b(s);
    }
    *(u16x8*)(ub + (size_t)(r0 + k) * 2048 + c8) = o;
  }
}

// ---- chunk-parallel scan, d-in-lane layout. 64 chunks x 32 steps. ----
// Q stored as bf16 (R6, verified: absmax unchanged).
__global__ __launch_bounds__(256)
void scan_s1(const u16* __restrict__ delta_bf, const u16* __restrict__ ub,
             const float* __restrict__ bc, const float* __restrict__ alog,
             u16* __restrict__ S, u16* __restrict__ Q)
{
  int blk = blockIdx.x;                // 1024 blocks: b(1) x c(6) x g(3)
  int g = blk & 7, c = (blk >> 3) & 63, b = blk >> 9;
  int d = g * 256 + threadIdx.x;
  float Av[16];
#pragma unroll
  for (int nq = 0; nq < 4; ++nq) {
    f4_t al = *(const f4_t*)(alog + (size_t)d * 16 + nq * 4);
#pragma unroll
    for (int j = 0; j < 4; ++j) Av[nq * 4 + j] = -__expf(al[j]);
  }
  float Av0 = Av[0];
  bool st = true;
#pragma unroll
  for (int n = 1; n < 16; ++n)
    st = st && (fabsf(Av[n] - (float)(n + 1) * Av0) <= 1e-3f * (float)(n + 1));
  f4_t Qr[4];
#pragma unroll
  for (int nq = 0; nq < 4; ++nq) Qr[nq] = {0.f,0.f,0.f,0.f};
  float Sd = 0.f;
  int row0 = b * 2048 + c * 32;
  if (st) {
#pragma unroll 2
    for (int i = 0; i < 32; ++i) {
      size_t row = (size_t)(row0 + i);
      float dlt = b2f(delta_bf[row * 2048 + d]);
      float uv  = b2f(ub[row * 2048 + d]);
      const float* bp = bc + row * 32;
      f4_t Bv[4];
#pragma unroll
      for (int nq = 0; nq < 4; ++nq) Bv[nq] = *(const f4_t*)(bp + nq * 4);
      float du = dlt * uv;
      float e1 = __expf(dlt * Av0);
      float a = e1;
      Sd += dlt;
#pragma unroll
      for (int n = 0; n < 16; ++n) {
        Qr[n >> 2][n & 3] = a * Qr[n >> 2][n & 3] + du * Bv[n >> 2][n & 3];
        a *= e1;
      }
    }
  } else {
#pragma unroll 2
    for (int i = 0; i < 32; ++i) {
      size_t row = (size_t)(row0 + i);
      float dlt = b2f(delta_bf[row * 2048 + d]);
      float uv  = b2f(ub[row * 2048 + d]);
      const float* bp = bc + row * 32;
      f4_t Bv[4];
#pragma unroll
      for (int nq = 0; nq < 4; ++nq) Bv[nq] = *(const f4_t*)(bp + nq * 4);
      float du = dlt * uv;
      Sd += dlt;
#pragma unroll
      for (int n = 0; n < 16; ++n) {
        float a = __expf(dlt * Av[n]);
        Qr[n >> 2][n & 3] = a * Qr[n >> 2][n & 3] + du * Bv[n >> 2][n & 3];
      }
    }
  }
  S[(size_t)(b * 64 + c) * 2048 + d] = f2b(Sd);
  size_t o = ((size_t)((b * 64 + c) * 2048 + d)) * 16;
  u16x8 q0, q1;
#pragma unroll
  for (int j = 0; j < 8; ++j) { q0[j] = f2b(Qr[j >> 2][j & 3]); q1[j] = f2b(Qr[(j + 8) >> 2][j & 3]); }
  *(u16x8*)(Q + o)     = q0;
  *(u16x8*)(Q + o + 8) = q1;
}

// S2: serial prefix over 64 chunks per (b,d,n); Q bf16 in/out
__global__ __launch_bounds__(256)
void scan_comb(const u16* __restrict__ S16, u16* __restrict__ Q,
               const float* __restrict__ alog)
{
  int idx = blockIdx.x * 256 + threadIdx.x;   // b*32768 + d*16+n
  int b = idx >> 15, dn = idx & 32767;
  int d = dn >> 4;
  float Av = -__expf(alog[dn]);
  size_t qbase = (size_t)b * 2097152 + dn;
  size_t sbase = (size_t)b * 131072 + d;
  float H = 0.f;
#pragma unroll
  for (int cg = 0; cg < 4; ++cg) {
    float sv[16], qv[16];
#pragma unroll
    for (int j = 0; j < 16; ++j) {
      int c = cg * 16 + j;
      qv[j] = b2f(Q[qbase + (size_t)c * 32768]);
      sv[j] = b2f(S16[sbase + (size_t)c * 2048]);
    }
#pragma unroll
    for (int j = 0; j < 16; ++j) {
      int c = cg * 16 + j;
      Q[qbase + (size_t)c * 32768] = f2b(H);
      H = __expf(Av * sv[j]) * H + qv[j];
    }
  }
}

// S3: re-scan with correct h_in (bf16 Q); fused D-skip + silu(z) gate
__global__ __launch_bounds__(256)
void scan_s3(const u16* __restrict__ delta_bf, const u16* __restrict__ ub,
             const float* __restrict__ bc, const float* __restrict__ alog,
             const u16* __restrict__ Q, const float* __restrict__ Dw,
             u16* __restrict__ zy)
{
  int blk = blockIdx.x;                // 1024 blocks
  int g = blk & 7, c = (blk >> 3) & 63, b = blk >> 9;
  int d = g * 256 + threadIdx.x;
  float Av[16];
#pragma unroll
  for (int nq = 0; nq < 4; ++nq) {
    f4_t al = *(const f4_t*)(alog + (size_t)d * 16 + nq * 4);
#pragma unroll
    for (int j = 0; j < 4; ++j) Av[nq * 4 + j] = -__expf(al[j]);
  }
  float Av0 = Av[0];
  bool st = true;
#pragma unroll
  for (int n = 1; n < 16; ++n)
    st = st && (fabsf(Av[n] - (float)(n + 1) * Av0) <= 1e-3f * (float)(n + 1));
  f4_t h4[4];
  size_t o = ((size_t)((b * 64 + c) * 2048 + d)) * 16;
  {
    u16x8 q0 = *(const u16x8*)(Q + o);
    u16x8 q1 = *(const u16x8*)(Q + o + 8);
#pragma unroll
    for (int j = 0; j < 8; ++j) { h4[j >> 2][j & 3] = b2f(q0[j]); h4[(j + 8) >> 2][j & 3] = b2f(q1[j]); }
  }
  float Dv = Dw[d];
  int row0 = b * 2048 + c * 32;
  if (st) {
#pragma unroll 2
    for (int i = 0; i < 32; ++i) {
      size_t row = (size_t)(row0 + i);
      float dlt = b2f(delta_bf[row * 2048 + d]);
      float uv  = b2f(ub[row * 2048 + d]);
      const float* bp = bc + row * 32;
      f4_t Bv[4], Cv[4];
#pragma unroll
      for (int nq = 0; nq < 4; ++nq) { Bv[nq] = *(const f4_t*)(bp + nq * 4); Cv[nq] = *(const f4_t*)(bp + 16 + nq * 4); }
      float du = dlt * uv;
      float e1 = __expf(dlt * Av0);
      float a = e1;
      float y = 0.f;
#pragma unroll
      for (int n = 0; n < 16; ++n) {
        float hn = a * h4[n >> 2][n & 3] + du * Bv[n >> 2][n & 3];
        h4[n >> 2][n & 3] = hn;
        y += hn * Cv[n >> 2][n & 3];
        a *= e1;
      }
      float zv = b2f(zy[row * 2048 + d]);
      float ov = (y + Dv * uv) * (zv / (1.f + __expf(-zv)));
      zy[row * 2048 + d] = f2b(ov);
    }
  } else {
#pragma unroll 2
    for (int i = 0; i < 32; ++i) {
      size_t row = (size_t)(row0 + i);
      float dlt = b2f(delta_bf[row * 2048 + d]);
      float uv  = b2f(ub[row * 2048 + d]);
      const float* bp = bc + row * 32;
      f4_t Bv[4], Cv[4];
#pragma unroll
      for (int nq = 0; nq < 4; ++nq) { Bv[nq] = *(const f4_t*)(bp + nq * 4); Cv[nq] = *(const f4_t*)(bp + 16 + nq * 4); }
      float du = dlt * uv;
      float y = 0.f;
#pragma unroll
      for (int n = 0; n < 16; ++n) {
        float a = __expf(dlt * Av[n]);
        float hn = a * h4[n >> 2][n & 3] + du * Bv[n >> 2][n & 3];
        h4[n >> 2][n & 3] = hn;
        y += hn * Cv[n >> 2][n & 3];
      }
      float zv = b2f(zy[row * 2048 + d]);
      float ov = (y + Dv * uv) * (zv / (1.f + __expf(-zv)));
      zy[row * 2048 + d] = f2b(ov);
    }
  }
}

// LayerNorm over h = y + x (bf16, residual added in gemm4_out epilogue).
__global__ __launch_bounds__(256)
void ln_kernel(const u16* __restrict__ hv,
               const float* __restrict__ lnw, const float* __restrict__ lnb,
               float* __restrict__ outp)
{
  __shared__ float ssum[4], ssq[4];
  int row = blockIdx.x, t = threadIdx.x;
  u16x4 hb = *(const u16x4*)(hv + (size_t)row * 1024 + t * 4);
  float v[4], s = 0.f, q = 0.f;
#pragma unroll
  for (int j = 0; j < 4; ++j) { v[j] = b2f(hb[j]); s += v[j]; q += v[j] * v[j]; }
#pragma unroll
  for (int m = 32; m; m >>= 1) { s += __shfl_xor(s, m, 64); q += __shfl_xor(q, m, 64); }
  int wv = t >> 6;
  if ((t & 63) == 0) { ssum[wv] = s; ssq[wv] = q; }
  __syncthreads();
  s = ssum[0] + ssum[1] + ssum[2] + ssum[3];
  q = ssq[0] + ssq[1] + ssq[2] + ssq[3];
  float mu = s * (1.f / 1024.f);
  float var = q * (1.f / 1024.f) - mu * mu;
  float rs = rsqrtf(var + 1e-5f);
  f4_t o;
#pragma unroll
  for (int j = 0; j < 4; ++j)
    o[j] = (v[j] - mu) * rs * lnw[t * 4 + j] + lnb[t * 4 + j];
  *(f4_t*)(outp + (size_t)row * 1024 + t * 4) = o;
}

extern "C" void kernel_launch(void* const* d_in, const int* in_sizes, int n_in,
                              void* d_out, int out_size, void* d_ws, size_t ws_size,
                              hipStream_t stream)
{
  const float* x      = (const float*)d_in[0];   // [2,2048,1024]
  const float* inW    = (const float*)d_in[1];   // [4096,1024]
  const float* convW  = (const float*)d_in[2];   // [2048,1,4]
  const float* convB  = (const float*)d_in[3];   // [2048]
  const float* xprojW = (const float*)d_in[4];   // [96,2048]
  const float* dtW    = (const float*)d_in[5];   // [2048,64]
  const float* dtB    = (const float*)d_in[6];   // [2048]
  const float* alog   = (const float*)d_in[7];   // [2048,16]
  const float* Dw     = (const float*)d_in[8];   // [2048]
  const float* outW   = (const float*)d_in[9];   // [1024,2048]
  const float* lnw    = (const float*)d_in[10];  // [1024]
  const float* lnb    = (const float*)d_in[11];  // [1024]
  float* out = (float*)d_out;                    // [2,2048,1024] f32 (16 MiB)

  char* ws = (char*)d_ws;
  u16*   xiz    = (u16*)(ws);
  u16*   zy     = xiz + 8388608;
  u16*   xb     = (u16*)(ws + 33554432);
  u16*   inWb   = xb + 4194304;
  u16*   u_bf   = (u16*)(ws + 33554432);          // overwrites xb/inWb after gemm8_in
  u16*   dtA    = (u16*)(ws + 50331648);
  float* bc     = (float*)(ws + 50855936);
  u16*   xprojWb= (u16*)(ws + 51380224);
  u16*   dtWb   = (u16*)(ws + 51773440);
  u16*   outWb  = (u16*)(ws + 52035584);
  u16*   delta  = xiz;                            // overwrites dead xi
  u16*   xpart  = (u16*)d_out;                    // x_proj bf16 partials [8][4096][96] = 6.3 MB
  u16*   Sbuf   = dtA;                            // S (dtA dead after gemm_dt)
  u16*   Qbuf   = (u16*)d_out;                    // Q bf16 [2,64,2048,16] = 8.39 MB
  u16*   hbuf   = (u16*)(ws);                     // h bf16 [4096,1024] = 8.4 MB (delta dead)

  dim3 blk(256);
  // fused f32 -> bf16 conversions (one launch)
  cvt_all<<<10560, blk, 0, stream>>>(x, inW, xprojW, dtW, outW,
                                     xb, inWb, xprojWb, dtWb, outWb);
  // in_proj: [4096,1024] x [4096,1024]^T -> xi | z (bf16); 8-phase 256^2 (R2)
  gemm8_in<<<dim3(16, 16), dim3(512), 0, stream>>>(xb, inWb, xiz);
  // depthwise causal conv + silu -> u (bf16; 4 rows/thread)
  conv_silu<<<1024, blk, 0, stream>>>(xiz, convW, convB, u_bf);
  // x_proj split-K (8 x 256): bf16 partials into d_out
  gemm_xp<<<dim3(8, 32), blk, 0, stream>>>(u_bf, 2048, xprojWb, 2048, 256, 96, xpart, nullptr);
  xproj_reduce<<<1536, blk, 0, stream>>>(xpart, dtA, bc);
  // dt_proj + softplus -> delta (bf16, overwrites xi)
  gemm_dt<<<dim3(16, 32), blk, 0, stream>>>(dtA, 64, dtWb, 64, 64, 2048, delta, dtB);
  // chunk-parallel scan (64 chunks x 32 steps): S1 -> combine -> S3 (Q bf16)
  scan_s1<<<1024, blk, 0, stream>>>(delta, u_bf, bc, alog, Sbuf, Qbuf);
  scan_comb<<<256, blk, 0, stream>>>(Sbuf, Qbuf, alog);
  scan_s3<<<1024, blk, 0, stream>>>(delta, u_bf, bc, alog, Qbuf, Dw, zy);
  // out_proj A-LDS/B-reg 128x128 + fused residual: h = bf16(y+x) -> ws
  gemm4_out<<<dim3(8, 32), blk, 0, stream>>>(zy, outWb, x, hbuf);
  // LayerNorm (bf16 h) -> f32 out
  ln_kernel<<<4096, blk, 0, stream>>>(hbuf, lnw, lnb, out);
}

// Round 10
// 281.448 us; speedup vs baseline: 1.0828x; 1.0828x over previous
//
#include <hip/hip_runtime.h>

typedef unsigned short u16;
typedef __attribute__((ext_vector_type(8))) short bf8_t;    // 8 x bf16 (4 VGPRs)
typedef __attribute__((ext_vector_type(4))) float f4_t;     // 4 x f32
typedef __attribute__((ext_vector_type(4))) unsigned short u16x4;
typedef __attribute__((ext_vector_type(8))) unsigned short u16x8;

__device__ __forceinline__ float b2f(u16 h) {
  union { unsigned u; float f; } v; v.u = ((unsigned)h) << 16; return v.f;
}
__device__ __forceinline__ u16 f2b(float f) {
  union { float f; unsigned u; } v; v.f = f;
  unsigned u = v.u;
  u += 0x7fffu + ((u >> 16) & 1u);   // round-nearest-even
  return (u16)(u >> 16);
}

#define AS1C(p) ((const __attribute__((address_space(1))) void*)(p))
#define AS3(p)  ((__attribute__((address_space(3))) void*)(p))

// one fused f32 -> bf16 convert over all 5 weight/input arrays
__global__ __launch_bounds__(256)
void cvt_all(const float* __restrict__ x, const float* __restrict__ inW,
             const float* __restrict__ xprojW, const float* __restrict__ dtW,
             const float* __restrict__ outW,
             u16* __restrict__ xb, u16* __restrict__ inWb, u16* __restrict__ xpb,
             u16* __restrict__ dtWb, u16* __restrict__ outWb)
{
  int i = blockIdx.x * 256 + threadIdx.x;      // float4 index, total 2703360
  if (i >= 2703360) return;
  const float* s; u16* d; int off;
  if (i < 1048576)      { s = x;      d = xb;    off = i; }
  else if (i < 2097152) { s = inW;    d = inWb;  off = i - 1048576; }
  else if (i < 2146304) { s = xprojW; d = xpb;   off = i - 2097152; }
  else if (i < 2179072) { s = dtW;    d = dtWb;  off = i - 2146304; }
  else                  { s = outW;   d = outWb; off = i - 2179072; }
  f4_t v = *(const f4_t*)(s + (size_t)off * 4);
  u16x4 o;
#pragma unroll
  for (int j = 0; j < 4; ++j) o[j] = f2b(v[j]);
  *(u16x4*)(d + (size_t)off * 4) = o;
}

// Stage one 128x64 bf16 tile (16 KB) into LDS, XOR-swizzled: granule (r,q)
// holds global colchunk q^(r&7). Staging lane i (chunk of 8 rows) fetches
// colchunk (i&7)^((i>>3)&7); reader uses granule (g ^ (row&7)). Bank-quad
// depends only on q_l -> 8 lanes per 4-bank group = 2/bank = conflict-free.
__device__ __forceinline__ void stage64(const u16* g, int ld, int row0, int rowmax,
                                        int k0, u16* lds, int wid, int lane) {
  int qg = (lane & 7) ^ ((lane >> 3) & 7);
#pragma unroll
  for (int c = 0; c < 4; ++c) {
    int chunk = wid * 4 + c;
    int r = row0 + chunk * 8 + (lane >> 3);
    if (r > rowmax) r = rowmax;                       // clamp (results discarded later)
    const u16* gp = g + (size_t)r * ld + k0 + qg * 8;
    __builtin_amdgcn_global_load_lds(AS1C(gp), AS3(lds + chunk * 512), 16, 0, 0);
  }
}

// C = A * Bt^T : A[M,K] bf16 row-major (lda), Bt[N,K] bf16 row-major (ldb).
// BK=64 (two 32-k half-steps per barrier epoch).
// EPI 1: x_proj   -> split-K partials in BF16: o16[(bx*4096+m)*96+n], n<96
// EPI 2: dt_proj  -> o16[m*2048+n] = bf16(softplus(acc + biasf[n]))
template<int EPI>
__device__ __forceinline__ void gemm_body(const u16* __restrict__ A, int lda,
             const u16* __restrict__ Bt, int ldb,
             int Kblk, int Nact,
             u16* __restrict__ o16, const float* __restrict__ biasf)
{
  __shared__ u16 lsA[128 * 64];
  __shared__ u16 lsB[128 * 64];
  const int tid = threadIdx.x;
  const int wid = tid >> 6, lane = tid & 63;
  const int wm = wid >> 1, wn = wid & 1;          // 2x2 wave grid, 64x64 each
  const int lrow = lane & 15;
  const int kq = lane >> 4;                       // 0..3
  const int sw = lrow & 7;                        // swizzle key
  const int m0 = blockIdx.y * 128;
  const int n0 = (EPI == 1) ? 0 : blockIdx.x * 128;
  int kbase = 0;
  if (EPI == 1) kbase = blockIdx.x * Kblk;

  f4_t acc[4][4];
#pragma unroll
  for (int i = 0; i < 4; ++i)
#pragma unroll
    for (int j = 0; j < 4; ++j) acc[i][j] = {0.f, 0.f, 0.f, 0.f};

  for (int kt = kbase; kt < kbase + Kblk; kt += 64) {
    stage64(A,  lda, m0, 0x3fffffff, kt, lsA, wid, lane);
    stage64(Bt, ldb, n0, Nact - 1,   kt, lsB, wid, lane);
    __syncthreads();
#pragma unroll
    for (int h = 0; h < 2; ++h) {
      const int lk = ((h * 4 + kq) ^ sw) * 8;
      bf8_t af[4], bfr[4];
#pragma unroll
      for (int mi = 0; mi < 4; ++mi)
        af[mi] = *(const bf8_t*)&lsA[(wm * 64 + mi * 16 + lrow) * 64 + lk];
#pragma unroll
      for (int ni = 0; ni < 4; ++ni)
        bfr[ni] = *(const bf8_t*)&lsB[(wn * 64 + ni * 16 + lrow) * 64 + lk];
#pragma unroll
      for (int mi = 0; mi < 4; ++mi)
#pragma unroll
        for (int ni = 0; ni < 4; ++ni)
          acc[mi][ni] = __builtin_amdgcn_mfma_f32_16x16x32_bf16(af[mi], bfr[ni], acc[mi][ni], 0, 0, 0);
    }
    __syncthreads();
  }

  const int rq = (lane >> 4) * 4;                  // C/D: row=(lane>>4)*4+r, col=lane&15
#pragma unroll
  for (int mi = 0; mi < 4; ++mi) {
#pragma unroll
    for (int ni = 0; ni < 4; ++ni) {
#pragma unroll
      for (int r = 0; r < 4; ++r) {
        int m = m0 + wm * 64 + mi * 16 + rq + r;
        int n = n0 + wn * 64 + ni * 16 + lrow;
        float v = acc[mi][ni][r];
        if (EPI == 1) {
          if (n < 96) o16[((size_t)blockIdx.x * 4096 + m) * 96 + n] = f2b(v);
        } else if (EPI == 2) {
          float t = v + biasf[n];
          float sp = (t > 20.f) ? t : log1pf(__expf(t));
          o16[(size_t)m * 2048 + n] = f2b(sp);
        }
      }
    }
  }
}

__global__ __launch_bounds__(256)
void gemm_xp(const u16* A, int lda, const u16* Bt, int ldb, int Kblk, int Nact,
             u16* o16, const float* biasf)
{ gemm_body<1>(A, lda, Bt, ldb, Kblk, Nact, o16, biasf); }

__global__ __launch_bounds__(256)
void gemm_dt(const u16* A, int lda, const u16* Bt, int ldb, int Kblk, int Nact,
             u16* o16, const float* biasf)
{ gemm_body<2>(A, lda, Bt, ldb, Kblk, Nact, o16, biasf); }

// ---------------------------------------------------------------------------
// 8-phase 256x256 bf16 GEMM for in_proj (M=N=4096, K=1024): verified R1/R2
// (42.1-42.3 us, 826 TF). Structure ceiling analysis (R5): acc[8][4]=128 f32
// -> ~256 unified regs/wave -> hard 1 block/CU; 128^2 tiles would be LDS-BW
// bound (~38 us); intra-block schedule perturbations null (R3/R4). Final.
// ---------------------------------------------------------------------------

// stage one 128x64 unit: 512 threads x 2 x 16B gload_lds. granule g = j*512 +
// wid*64 + lane -> lds row g>>3, slot g&7, global colchunk (g&7)^((g>>3)&7).
__device__ __forceinline__ void stageu(const u16* __restrict__ g, int ld,
                                       int row0, int k0, u16* ldsu,
                                       int wid, int lane) {
  int qg = (lane & 7) ^ ((lane >> 3) & 7);
#pragma unroll
  for (int j = 0; j < 2; ++j) {
    int rr = j * 64 + wid * 8 + (lane >> 3);
    const u16* gp = g + (size_t)(row0 + rr) * ld + k0 + qg * 8;
    __builtin_amdgcn_global_load_lds(AS1C(gp), AS3(ldsu + (j * 512 + wid * 64) * 8), 16, 0, 0);
  }
}

#define G8_BAR()   __builtin_amdgcn_s_barrier()
#define G8_LGKM0() do { asm volatile("s_waitcnt lgkmcnt(0)" ::: "memory"); \
                        __builtin_amdgcn_sched_barrier(0); } while (0)
#define G8_LGKM8() asm volatile("s_waitcnt lgkmcnt(8)" ::: "memory")
#define G8_VM(N)   do { asm volatile("s_waitcnt vmcnt(" #N ")" ::: "memory"); \
                        __builtin_amdgcn_sched_barrier(0); } while (0)

#define RD_A(base, MH) do { \
  _Pragma("unroll") \
  for (int mi_ = 0; mi_ < 4; ++mi_) { \
    af[mi_][0] = *(const bf8_t*)((base) + arow + ((MH) * 64 + mi_ * 16) * 64 + aq0); \
    af[mi_][1] = *(const bf8_t*)((base) + arow + ((MH) * 64 + mi_ * 16) * 64 + aq1); \
  } } while (0)

#define RD_B(base, NH) do { \
  _Pragma("unroll") \
  for (int ni_ = 0; ni_ < 2; ++ni_) { \
    bfr[NH][ni_][0] = *(const bf8_t*)((base) + brow + ((NH) * 32 + ni_ * 16) * 64 + aq0); \
    bfr[NH][ni_][1] = *(const bf8_t*)((base) + brow + ((NH) * 32 + ni_ * 16) * 64 + aq1); \
  } } while (0)

#define MMA(MH, NH) do { \
  __builtin_amdgcn_s_setprio(1); \
  _Pragma("unroll") \
  for (int mi_ = 0; mi_ < 4; ++mi_) \
    _Pragma("unroll") \
    for (int ni_ = 0; ni_ < 2; ++ni_) { \
      acc[(MH) * 4 + mi_][(NH) * 2 + ni_] = __builtin_amdgcn_mfma_f32_16x16x32_bf16( \
          af[mi_][0], bfr[NH][ni_][0], acc[(MH) * 4 + mi_][(NH) * 2 + ni_], 0, 0, 0); \
      acc[(MH) * 4 + mi_][(NH) * 2 + ni_] = __builtin_amdgcn_mfma_f32_16x16x32_bf16( \
          af[mi_][1], bfr[NH][ni_][1], acc[(MH) * 4 + mi_][(NH) * 2 + ni_], 0, 0, 0); \
    } \
  __builtin_amdgcn_s_setprio(0); \
} while (0)

__global__ __launch_bounds__(512, 2)
void gemm8_in(const u16* __restrict__ A, const u16* __restrict__ Bt,
              u16* __restrict__ o16)
{
  __shared__ u16 ls[65536];                       // 128 KB: 2 buf x (A 32K + B 32K)
  const int tid = threadIdx.x;
  const int wid = tid >> 6, lane = tid & 63;
  const int wm = wid >> 2, wn = wid & 3;          // 2x4 wave grid, 128x64 per wave
  const int lrow = lane & 15;
  const int kq = lane >> 4;
  const int sw = lrow & 7;
  const int m0 = blockIdx.y * 256;
  const int n0 = blockIdx.x * 256;
  u16* lsA0 = ls;
  u16* lsB0 = ls + 16384;
  u16* lsA1 = ls + 32768;
  u16* lsB1 = ls + 49152;
  const int arow = (wm * 128 + lrow) * 64;
  const int brow = (wn * 64 + lrow) * 64;
  const int aq0 = (kq ^ sw) * 8;
  const int aq1 = ((4 + kq) ^ sw) * 8;

  f4_t acc[8][4];
#pragma unroll
  for (int i = 0; i < 8; ++i)
#pragma unroll
    for (int j = 0; j < 4; ++j) acc[i][j] = {0.f, 0.f, 0.f, 0.f};
  bf8_t af[4][2];
  bf8_t bfr[2][2][2];

  // prologue: tile0 (A0,A1,B0,B1)->buf0, tile1 (B0,B1)->buf1; keep 4 in flight
  stageu(A,  1024, m0,        0, lsA0,        wid, lane);
  stageu(A,  1024, m0 + 128,  0, lsA0 + 8192, wid, lane);
  stageu(Bt, 1024, n0,        0, lsB0,        wid, lane);
  stageu(Bt, 1024, n0 + 128,  0, lsB0 + 8192, wid, lane);
  stageu(Bt, 1024, n0,       64, lsB1,        wid, lane);
  stageu(Bt, 1024, n0 + 128, 64, lsB1 + 8192, wid, lane);
  G8_VM(4); G8_BAR();

#pragma unroll 1
  for (int i = 0; i < 7; ++i) {                   // iterations 0..6 (tiles 0..13)
    const int k1 = (2 * i + 1) * 64, k2 = k1 + 64, k3 = k1 + 128;
    // P1: read buf0 A-half0 + B-half0; stage (t+1).A0 -> buf1
    RD_A(lsA0, 0); RD_B(lsB0, 0);
    stageu(A, 1024, m0, k1, lsA1, wid, lane);
    G8_LGKM8(); G8_BAR(); G8_LGKM0(); MMA(0, 0); G8_BAR();
    // P2: read buf0 B-half1; stage (t+1).A1 -> buf1
    RD_B(lsB0, 1);
    stageu(A, 1024, m0 + 128, k1, lsA1 + 8192, wid, lane);
    G8_BAR(); G8_LGKM0(); MMA(0, 1); G8_BAR();
    // P3: read buf0 A-half1; stage (t+2).B0 -> buf0 (B reads done end P2)
    RD_A(lsA0, 1);
    stageu(Bt, 1024, n0, k2, lsB0, wid, lane);
    G8_BAR(); G8_LGKM0(); MMA(1, 0); G8_BAR();
    // P4: stage (t+2).B1 -> buf0; counted vmcnt -> tile t+1 landed
    stageu(Bt, 1024, n0 + 128, k2, lsB0 + 8192, wid, lane);
    G8_BAR(); G8_LGKM0(); MMA(1, 1); G8_VM(4); G8_BAR();
    // P5: read buf1 A-half0 + B-half0; stage (t+2).A0 -> buf0 (A reads done end P3)
    RD_A(lsA1, 0); RD_B(lsB1, 0);
    stageu(A, 1024, m0, k2, lsA0, wid, lane);
    G8_LGKM8(); G8_BAR(); G8_LGKM0(); MMA(0, 0); G8_BAR();
    // P6: read buf1 B-half1; stage (t+2).A1 -> buf0
    RD_B(lsB1, 1);
    stageu(A, 1024, m0 + 128, k2, lsA0 + 8192, wid, lane);
    G8_BAR(); G8_LGKM0(); MMA(0, 1); G8_BAR();
    // P7: read buf1 A-half1; stage (t+3).B0 -> buf1
    RD_A(lsA1, 1);
    stageu(Bt, 1024, n0, k3, lsB1, wid, lane);
    G8_BAR(); G8_LGKM0(); MMA(1, 0); G8_BAR();
    // P8: stage (t+3).B1 -> buf1; counted vmcnt -> tile t+2 landed
    stageu(Bt, 1024, n0 + 128, k3, lsB1 + 8192, wid, lane);
    G8_BAR(); G8_LGKM0(); MMA(1, 1); G8_VM(4); G8_BAR();
  }

  {                                               // last iteration: tiles 14,15
    const int k1 = 960;
    RD_A(lsA0, 0); RD_B(lsB0, 0);
    stageu(A, 1024, m0, k1, lsA1, wid, lane);
    G8_LGKM8(); G8_BAR(); G8_LGKM0(); MMA(0, 0); G8_BAR();
    RD_B(lsB0, 1);
    stageu(A, 1024, m0 + 128, k1, lsA1 + 8192, wid, lane);
    G8_BAR(); G8_LGKM0(); MMA(0, 1); G8_BAR();
    RD_A(lsA0, 1);
    G8_BAR(); G8_LGKM0(); MMA(1, 0); G8_BAR();
    G8_BAR(); G8_LGKM0(); MMA(1, 1); G8_VM(0); G8_BAR();
    RD_A(lsA1, 0); RD_B(lsB1, 0);
    G8_BAR(); G8_LGKM0(); MMA(0, 0); G8_BAR();
    RD_B(lsB1, 1);
    G8_BAR(); G8_LGKM0(); MMA(0, 1); G8_BAR();
    RD_A(lsA1, 1);
    G8_BAR(); G8_LGKM0(); MMA(1, 0); G8_BAR();
    G8_LGKM0(); MMA(1, 1);
  }

  // epilogue: xi (n<2048) | z (n>=2048, at o16+8M)
  const int rq = (lane >> 4) * 4;
#pragma unroll
  for (int mi = 0; mi < 8; ++mi) {
#pragma unroll
    for (int ni = 0; ni < 4; ++ni) {
#pragma unroll
      for (int r = 0; r < 4; ++r) {
        int m = m0 + wm * 128 + mi * 16 + rq + r;
        int n = n0 + wn * 64 + ni * 16 + lrow;
        float v = acc[mi][ni][r];
        if (n < 2048) o16[(size_t)m * 2048 + n] = f2b(v);
        else          o16[(size_t)8388608 + (size_t)m * 2048 + (n - 2048)] = f2b(v);
      }
    }
  }
}

// ---------------------------------------------------------------------------
// out_proj: single-K 4-phase GEMM, 256 threads (2x2 waves of 64x64, 16 MFMA
// per cluster), tile 128M x 128N, K=2048, grid (8,32)=256 blocks, 2 blk/CU.
// A and B both LDS-staged (R8-verified best: 283.1 us total). R9's B-in-reg
// variant REGRESSED (FETCH 30->76 MB, MfmaUtil 12%): per-lane B loads scatter
// 64 lanes across 16 rows -> uncoalesced; do NOT bypass LDS for B here.
// Fused residual + bf16 h output: epilogue writes h = bf16(y + x).
// ---------------------------------------------------------------------------

#define X4_RD_A(base, KH) do { \
  _Pragma("unroll") \
  for (int mi_ = 0; mi_ < 4; ++mi_) \
    afx[mi_] = *(const bf8_t*)((base) + (wm * 64 + mi_ * 16 + lrow) * 64 + ((KH) ? aq1 : aq0)); \
  } while (0)

#define X4_RD_B(base) do { \
  _Pragma("unroll") \
  for (int ni_ = 0; ni_ < 4; ++ni_) { \
    bfx[ni_][0] = *(const bf8_t*)((base) + (wn * 64 + ni_ * 16 + lrow) * 64 + aq0); \
    bfx[ni_][1] = *(const bf8_t*)((base) + (wn * 64 + ni_ * 16 + lrow) * 64 + aq1); \
  } } while (0)

#define X4_MMA(KH) do { \
  __builtin_amdgcn_s_setprio(1); \
  _Pragma("unroll") \
  for (int mi_ = 0; mi_ < 4; ++mi_) \
    _Pragma("unroll") \
    for (int ni_ = 0; ni_ < 4; ++ni_) \
      acc[mi_][ni_] = __builtin_amdgcn_mfma_f32_16x16x32_bf16( \
          afx[mi_], bfx[ni_][KH], acc[mi_][ni_], 0, 0, 0); \
  __builtin_amdgcn_s_setprio(0); \
} while (0)

__global__ __launch_bounds__(256, 2)
void gemm4_out(const u16* __restrict__ A, const u16* __restrict__ Bt,
               const float* __restrict__ xres, u16* __restrict__ hout)
{
  __shared__ u16 ls[32768];                       // 64 KB: 2 buf x (A 16K + B 16K)
  const int tid = threadIdx.x;
  const int wid = tid >> 6, lane = tid & 63;
  const int wm = wid >> 1, wn = wid & 1;          // 2x2 waves, 64x64 each
  const int lrow = lane & 15;
  const int kq = lane >> 4;
  const int sw = lrow & 7;
  const int m0 = blockIdx.y * 128;
  const int n0 = blockIdx.x * 128;
  u16* lsA0 = ls;                                 // 8192 u16 = 128x64
  u16* lsB0 = ls + 8192;
  u16* lsA1 = ls + 16384;
  u16* lsB1 = ls + 24576;
  const int aq0 = (kq ^ sw) * 8;
  const int aq1 = ((4 + kq) ^ sw) * 8;

  f4_t acc[4][4];
#pragma unroll
  for (int i = 0; i < 4; ++i)
#pragma unroll
    for (int j = 0; j < 4; ++j) acc[i][j] = {0.f, 0.f, 0.f, 0.f};
  bf8_t afx[4];
  bf8_t bfx[4][2];

  // prologue: tile0 (A,B)->buf0, tile1 B->buf1
  stage64(A,  2048, m0, 0x3fffffff,  0, lsA0, wid, lane);
  stage64(Bt, 2048, n0, 0x3fffffff,  0, lsB0, wid, lane);
  stage64(Bt, 2048, n0, 0x3fffffff, 64, lsB1, wid, lane);
  G8_VM(4); G8_BAR();

#pragma unroll 1
  for (int i = 0; i < 15; ++i) {                  // tile pairs (0,1)..(28,29)
    const int ka1 = (2 * i + 1) * 64;             // A of odd tile t+1
    const int k2  = ka1 + 64;                     // tile t+2
    const int kb3 = ka1 + 128;                    // B of tile t+3
    // Q1: read buf0 {A-kh0, B both}; stage A(t+1)->buf1.A (sealed prev Q4)
    X4_RD_A(lsA0, 0); X4_RD_B(lsB0);
    stage64(A, 2048, m0, 0x3fffffff, ka1, lsA1, wid, lane);
    G8_BAR(); G8_LGKM0(); X4_MMA(0); G8_BAR();
    // Q2: read buf0 A-kh1; stage B(t+2)->buf0.B (sealed end Q1)
    X4_RD_A(lsA0, 1);
    stage64(Bt, 2048, n0, 0x3fffffff, k2, lsB0, wid, lane);
    G8_LGKM0(); X4_MMA(1); G8_VM(4); G8_BAR();
    // Q3: read buf1 {A-kh0, B both}; stage A(t+2)->buf0.A (sealed end Q2)
    X4_RD_A(lsA1, 0); X4_RD_B(lsB1);
    stage64(A, 2048, m0, 0x3fffffff, k2, lsA0, wid, lane);
    G8_BAR(); G8_LGKM0(); X4_MMA(0); G8_BAR();
    // Q4: read buf1 A-kh1; stage B(t+3)->buf1.B (sealed end Q3)
    X4_RD_A(lsA1, 1);
    stage64(Bt, 2048, n0, 0x3fffffff, kb3, lsB1, wid, lane);
    G8_LGKM0(); X4_MMA(1); G8_VM(4); G8_BAR();
  }

  {                                               // final: tiles 30, 31
    X4_RD_A(lsA0, 0); X4_RD_B(lsB0);
    stage64(A, 2048, m0, 0x3fffffff, 1984, lsA1, wid, lane);   // A(31)
    G8_BAR(); G8_LGKM0(); X4_MMA(0); G8_BAR();
    X4_RD_A(lsA0, 1);
    G8_LGKM0(); X4_MMA(1); G8_VM(0); G8_BAR();    // drain A(31),B(31)
    X4_RD_A(lsA1, 0); X4_RD_B(lsB1);
    G8_LGKM0(); X4_MMA(0);
    X4_RD_A(lsA1, 1);
    G8_LGKM0(); X4_MMA(1);
  }

  const int rq = (lane >> 4) * 4;
#pragma unroll
  for (int mi = 0; mi < 4; ++mi) {
#pragma unroll
    for (int ni = 0; ni < 4; ++ni) {
#pragma unroll
      for (int r = 0; r < 4; ++r) {
        int m = m0 + wm * 64 + mi * 16 + rq + r;
        int n = n0 + wn * 64 + ni * 16 + lrow;
        hout[(size_t)m * 1024 + n] = f2b(acc[mi][ni][r] + xres[(size_t)m * 1024 + n]);
      }
    }
  }
}

// reduce 8 bf16 split-K partials of x_proj; emit dtA bf16 [4096,64] + bc f32 [4096,32]
__global__ __launch_bounds__(256)
void xproj_reduce(const u16* __restrict__ part, u16* __restrict__ dtA,
                  float* __restrict__ bc)
{
  int idx = blockIdx.x * 256 + threadIdx.x;   // 4096*96
  int m = idx / 96, n = idx - m * 96;
  float s = 0.f;
#pragma unroll
  for (int p = 0; p < 8; ++p) s += b2f(part[(size_t)p * 393216 + idx]);
  if (n < 64) dtA[(size_t)m * 64 + n] = f2b(s);
  else        bc[(size_t)m * 32 + (n - 64)] = s;
}

// causal depthwise conv1d (window 4) + bias + silu.
// 4 output rows per thread -> 7 row-loads per 4 outputs (verified R8).
__global__ __launch_bounds__(256)
void conv_silu(const u16* __restrict__ xib, const float* __restrict__ cw,
               const float* __restrict__ cb, u16* __restrict__ ub)
{
  int i = blockIdx.x * 256 + threadIdx.x;     // 262,144 threads
  int c8 = (i & 255) * 8;
  int r0 = (i >> 8) * 4;                      // rows r0..r0+3 (same batch)
  int l0 = r0 & 2047;
  const u16* base = xib + (size_t)r0 * 2048 + c8;
  u16x8 xr[7];
  u16x8 z8 = {0,0,0,0,0,0,0,0};
#pragma unroll
  for (int j = 0; j < 3; ++j)
    xr[j] = (l0 != 0) ? *(const u16x8*)(base + (j - 3) * 2048) : z8;
#pragma unroll
  for (int j = 3; j < 7; ++j)
    xr[j] = *(const u16x8*)(base + (j - 3) * 2048);
  f4_t cb0 = *(const f4_t*)(cb + c8);
  f4_t cb1 = *(const f4_t*)(cb + c8 + 4);
  f4_t w[8];
#pragma unroll
  for (int j = 0; j < 8; ++j) w[j] = *(const f4_t*)(cw + (size_t)(c8 + j) * 4);
#pragma unroll
  for (int k = 0; k < 4; ++k) {
    u16x8 o;
#pragma unroll
    for (int j = 0; j < 8; ++j) {
      float a = (j < 4 ? cb0[j] : cb1[j - 4])
              + w[j][0] * b2f(xr[k][j])     + w[j][1] * b2f(xr[k + 1][j])
              + w[j][2] * b2f(xr[k + 2][j]) + w[j][3] * b2f(xr[k + 3][j]);
      float s = a / (1.f + __expf(-a));
      o[j] = f2b(s);
    }
    *(u16x8*)(ub + (size_t)(r0 + k) * 2048 + c8) = o;
  }
}

// ---- chunk-parallel scan, d-in-lane layout. 64 chunks x 32 steps. ----
// Q stored as bf16 (R6, verified: absmax unchanged).
__global__ __launch_bounds__(256)
void scan_s1(const u16* __restrict__ delta_bf, const u16* __restrict__ ub,
             const float* __restrict__ bc, const float* __restrict__ alog,
             u16* __restrict__ S, u16* __restrict__ Q)
{
  int blk = blockIdx.x;                // 1024 blocks: b(1) x c(6) x g(3)
  int g = blk & 7, c = (blk >> 3) & 63, b = blk >> 9;
  int d = g * 256 + threadIdx.x;
  float Av[16];
#pragma unroll
  for (int nq = 0; nq < 4; ++nq) {
    f4_t al = *(const f4_t*)(alog + (size_t)d * 16 + nq * 4);
#pragma unroll
    for (int j = 0; j < 4; ++j) Av[nq * 4 + j] = -__expf(al[j]);
  }
  float Av0 = Av[0];
  bool st = true;
#pragma unroll
  for (int n = 1; n < 16; ++n)
    st = st && (fabsf(Av[n] - (float)(n + 1) * Av0) <= 1e-3f * (float)(n + 1));
  f4_t Qr[4];
#pragma unroll
  for (int nq = 0; nq < 4; ++nq) Qr[nq] = {0.f,0.f,0.f,0.f};
  float Sd = 0.f;
  int row0 = b * 2048 + c * 32;
  if (st) {
#pragma unroll 2
    for (int i = 0; i < 32; ++i) {
      size_t row = (size_t)(row0 + i);
      float dlt = b2f(delta_bf[row * 2048 + d]);
      float uv  = b2f(ub[row * 2048 + d]);
      const float* bp = bc + row * 32;
      f4_t Bv[4];
#pragma unroll
      for (int nq = 0; nq < 4; ++nq) Bv[nq] = *(const f4_t*)(bp + nq * 4);
      float du = dlt * uv;
      float e1 = __expf(dlt * Av0);
      float a = e1;
      Sd += dlt;
#pragma unroll
      for (int n = 0; n < 16; ++n) {
        Qr[n >> 2][n & 3] = a * Qr[n >> 2][n & 3] + du * Bv[n >> 2][n & 3];
        a *= e1;
      }
    }
  } else {
#pragma unroll 2
    for (int i = 0; i < 32; ++i) {
      size_t row = (size_t)(row0 + i);
      float dlt = b2f(delta_bf[row * 2048 + d]);
      float uv  = b2f(ub[row * 2048 + d]);
      const float* bp = bc + row * 32;
      f4_t Bv[4];
#pragma unroll
      for (int nq = 0; nq < 4; ++nq) Bv[nq] = *(const f4_t*)(bp + nq * 4);
      float du = dlt * uv;
      Sd += dlt;
#pragma unroll
      for (int n = 0; n < 16; ++n) {
        float a = __expf(dlt * Av[n]);
        Qr[n >> 2][n & 3] = a * Qr[n >> 2][n & 3] + du * Bv[n >> 2][n & 3];
      }
    }
  }
  S[(size_t)(b * 64 + c) * 2048 + d] = f2b(Sd);
  size_t o = ((size_t)((b * 64 + c) * 2048 + d)) * 16;
  u16x8 q0, q1;
#pragma unroll
  for (int j = 0; j < 8; ++j) { q0[j] = f2b(Qr[j >> 2][j & 3]); q1[j] = f2b(Qr[(j + 8) >> 2][j & 3]); }
  *(u16x8*)(Q + o)     = q0;
  *(u16x8*)(Q + o + 8) = q1;
}

// S2: serial prefix over 64 chunks per (b,d,n); Q bf16 in/out
__global__ __launch_bounds__(256)
void scan_comb(const u16* __restrict__ S16, u16* __restrict__ Q,
               const float* __restrict__ alog)
{
  int idx = blockIdx.x * 256 + threadIdx.x;   // b*32768 + d*16+n
  int b = idx >> 15, dn = idx & 32767;
  int d = dn >> 4;
  float Av = -__expf(alog[dn]);
  size_t qbase = (size_t)b * 2097152 + dn;
  size_t sbase = (size_t)b * 131072 + d;
  float H = 0.f;
#pragma unroll
  for (int cg = 0; cg < 4; ++cg) {
    float sv[16], qv[16];
#pragma unroll
    for (int j = 0; j < 16; ++j) {
      int c = cg * 16 + j;
      qv[j] = b2f(Q[qbase + (size_t)c * 32768]);
      sv[j] = b2f(S16[sbase + (size_t)c * 2048]);
    }
#pragma unroll
    for (int j = 0; j < 16; ++j) {
      int c = cg * 16 + j;
      Q[qbase + (size_t)c * 32768] = f2b(H);
      H = __expf(Av * sv[j]) * H + qv[j];
    }
  }
}

// S3: re-scan with correct h_in (bf16 Q); fused D-skip + silu(z) gate
__global__ __launch_bounds__(256)
void scan_s3(const u16* __restrict__ delta_bf, const u16* __restrict__ ub,
             const float* __restrict__ bc, const float* __restrict__ alog,
             const u16* __restrict__ Q, const float* __restrict__ Dw,
             u16* __restrict__ zy)
{
  int blk = blockIdx.x;                // 1024 blocks
  int g = blk & 7, c = (blk >> 3) & 63, b = blk >> 9;
  int d = g * 256 + threadIdx.x;
  float Av[16];
#pragma unroll
  for (int nq = 0; nq < 4; ++nq) {
    f4_t al = *(const f4_t*)(alog + (size_t)d * 16 + nq * 4);
#pragma unroll
    for (int j = 0; j < 4; ++j) Av[nq * 4 + j] = -__expf(al[j]);
  }
  float Av0 = Av[0];
  bool st = true;
#pragma unroll
  for (int n = 1; n < 16; ++n)
    st = st && (fabsf(Av[n] - (float)(n + 1) * Av0) <= 1e-3f * (float)(n + 1));
  f4_t h4[4];
  size_t o = ((size_t)((b * 64 + c) * 2048 + d)) * 16;
  {
    u16x8 q0 = *(const u16x8*)(Q + o);
    u16x8 q1 = *(const u16x8*)(Q + o + 8);
#pragma unroll
    for (int j = 0; j < 8; ++j) { h4[j >> 2][j & 3] = b2f(q0[j]); h4[(j + 8) >> 2][j & 3] = b2f(q1[j]); }
  }
  float Dv = Dw[d];
  int row0 = b * 2048 + c * 32;
  if (st) {
#pragma unroll 2
    for (int i = 0; i < 32; ++i) {
      size_t row = (size_t)(row0 + i);
      float dlt = b2f(delta_bf[row * 2048 + d]);
      float uv  = b2f(ub[row * 2048 + d]);
      const float* bp = bc + row * 32;
      f4_t Bv[4], Cv[4];
#pragma unroll
      for (int nq = 0; nq < 4; ++nq) { Bv[nq] = *(const f4_t*)(bp + nq * 4); Cv[nq] = *(const f4_t*)(bp + 16 + nq * 4); }
      float du = dlt * uv;
      float e1 = __expf(dlt * Av0);
      float a = e1;
      float y = 0.f;
#pragma unroll
      for (int n = 0; n < 16; ++n) {
        float hn = a * h4[n >> 2][n & 3] + du * Bv[n >> 2][n & 3];
        h4[n >> 2][n & 3] = hn;
        y += hn * Cv[n >> 2][n & 3];
        a *= e1;
      }
      float zv = b2f(zy[row * 2048 + d]);
      float ov = (y + Dv * uv) * (zv / (1.f + __expf(-zv)));
      zy[row * 2048 + d] = f2b(ov);
    }
  } else {
#pragma unroll 2
    for (int i = 0; i < 32; ++i) {
      size_t row = (size_t)(row0 + i);
      float dlt = b2f(delta_bf[row * 2048 + d]);
      float uv  = b2f(ub[row * 2048 + d]);
      const float* bp = bc + row * 32;
      f4_t Bv[4], Cv[4];
#pragma unroll
      for (int nq = 0; nq < 4; ++nq) { Bv[nq] = *(const f4_t*)(bp + nq * 4); Cv[nq] = *(const f4_t*)(bp + 16 + nq * 4); }
      float du = dlt * uv;
      float y = 0.f;
#pragma unroll
      for (int n = 0; n < 16; ++n) {
        float a = __expf(dlt * Av[n]);
        float hn = a * h4[n >> 2][n & 3] + du * Bv[n >> 2][n & 3];
        h4[n >> 2][n & 3] = hn;
        y += hn * Cv[n >> 2][n & 3];
      }
      float zv = b2f(zy[row * 2048 + d]);
      float ov = (y + Dv * uv) * (zv / (1.f + __expf(-zv)));
      zy[row * 2048 + d] = f2b(ov);
    }
  }
}

// LayerNorm over h = y + x (bf16, residual added in gemm4_out epilogue).
__global__ __launch_bounds__(256)
void ln_kernel(const u16* __restrict__ hv,
               const float* __restrict__ lnw, const float* __restrict__ lnb,
               float* __restrict__ outp)
{
  __shared__ float ssum[4], ssq[4];
  int row = blockIdx.x, t = threadIdx.x;
  u16x4 hb = *(const u16x4*)(hv + (size_t)row * 1024 + t * 4);
  float v[4], s = 0.f, q = 0.f;
#pragma unroll
  for (int j = 0; j < 4; ++j) { v[j] = b2f(hb[j]); s += v[j]; q += v[j] * v[j]; }
#pragma unroll
  for (int m = 32; m; m >>= 1) { s += __shfl_xor(s, m, 64); q += __shfl_xor(q, m, 64); }
  int wv = t >> 6;
  if ((t & 63) == 0) { ssum[wv] = s; ssq[wv] = q; }
  __syncthreads();
  s = ssum[0] + ssum[1] + ssum[2] + ssum[3];
  q = ssq[0] + ssq[1] + ssq[2] + ssq[3];
  float mu = s * (1.f / 1024.f);
  float var = q * (1.f / 1024.f) - mu * mu;
  float rs = rsqrtf(var + 1e-5f);
  f4_t o;
#pragma unroll
  for (int j = 0; j < 4; ++j)
    o[j] = (v[j] - mu) * rs * lnw[t * 4 + j] + lnb[t * 4 + j];
  *(f4_t*)(outp + (size_t)row * 1024 + t * 4) = o;
}

extern "C" void kernel_launch(void* const* d_in, const int* in_sizes, int n_in,
                              void* d_out, int out_size, void* d_ws, size_t ws_size,
                              hipStream_t stream)
{
  const float* x      = (const float*)d_in[0];   // [2,2048,1024]
  const float* inW    = (const float*)d_in[1];   // [4096,1024]
  const float* convW  = (const float*)d_in[2];   // [2048,1,4]
  const float* convB  = (const float*)d_in[3];   // [2048]
  const float* xprojW = (const float*)d_in[4];   // [96,2048]
  const float* dtW    = (const float*)d_in[5];   // [2048,64]
  const float* dtB    = (const float*)d_in[6];   // [2048]
  const float* alog   = (const float*)d_in[7];   // [2048,16]
  const float* Dw     = (const float*)d_in[8];   // [2048]
  const float* outW   = (const float*)d_in[9];   // [1024,2048]
  const float* lnw    = (const float*)d_in[10];  // [1024]
  const float* lnb    = (const float*)d_in[11];  // [1024]
  float* out = (float*)d_out;                    // [2,2048,1024] f32 (16 MiB)

  char* ws = (char*)d_ws;
  u16*   xiz    = (u16*)(ws);
  u16*   zy     = xiz + 8388608;
  u16*   xb     = (u16*)(ws + 33554432);
  u16*   inWb   = xb + 4194304;
  u16*   u_bf   = (u16*)(ws + 33554432);          // overwrites xb/inWb after gemm8_in
  u16*   dtA    = (u16*)(ws + 50331648);
  float* bc     = (float*)(ws + 50855936);
  u16*   xprojWb= (u16*)(ws + 51380224);
  u16*   dtWb   = (u16*)(ws + 51773440);
  u16*   outWb  = (u16*)(ws + 52035584);
  u16*   delta  = xiz;                            // overwrites dead xi
  u16*   xpart  = (u16*)d_out;                    // x_proj bf16 partials [8][4096][96] = 6.3 MB
  u16*   Sbuf   = dtA;                            // S (dtA dead after gemm_dt)
  u16*   Qbuf   = (u16*)d_out;                    // Q bf16 [2,64,2048,16] = 8.39 MB
  u16*   hbuf   = (u16*)(ws);                     // h bf16 [4096,1024] = 8.4 MB (delta dead)

  dim3 blk(256);
  // fused f32 -> bf16 conversions (one launch)
  cvt_all<<<10560, blk, 0, stream>>>(x, inW, xprojW, dtW, outW,
                                     xb, inWb, xprojWb, dtWb, outWb);
  // in_proj: [4096,1024] x [4096,1024]^T -> xi | z (bf16); 8-phase 256^2 (R2)
  gemm8_in<<<dim3(16, 16), dim3(512), 0, stream>>>(xb, inWb, xiz);
  // depthwise causal conv + silu -> u (bf16; 4 rows/thread)
  conv_silu<<<1024, blk, 0, stream>>>(xiz, convW, convB, u_bf);
  // x_proj split-K (8 x 256): bf16 partials into d_out
  gemm_xp<<<dim3(8, 32), blk, 0, stream>>>(u_bf, 2048, xprojWb, 2048, 256, 96, xpart, nullptr);
  xproj_reduce<<<1536, blk, 0, stream>>>(xpart, dtA, bc);
  // dt_proj + softplus -> delta (bf16, overwrites xi)
  gemm_dt<<<dim3(16, 32), blk, 0, stream>>>(dtA, 64, dtWb, 64, 64, 2048, delta, dtB);
  // chunk-parallel scan (64 chunks x 32 steps): S1 -> combine -> S3 (Q bf16)
  scan_s1<<<1024, blk, 0, stream>>>(delta, u_bf, bc, alog, Sbuf, Qbuf);
  scan_comb<<<256, blk, 0, stream>>>(Sbuf, Qbuf, alog);
  scan_s3<<<1024, blk, 0, stream>>>(delta, u_bf, bc, alog, Qbuf, Dw, zy);
  // out_proj single-K 4-phase 128x128 (A+B LDS) + fused residual: h = bf16(y+x)
  gemm4_out<<<dim3(8, 32), blk, 0, stream>>>(zy, outWb, x, hbuf);
  // LayerNorm (bf16 h) -> f32 out
  ln_kernel<<<4096, blk, 0, stream>>>(hbuf, lnw, lnb, out);
}